// Round 1
// baseline (628.802 us; speedup 1.0000x reference)
//
#include <hip/hip_runtime.h>

typedef unsigned int uint;
typedef unsigned short ushort;
typedef __attribute__((ext_vector_type(4))) float f32x4;
typedef __attribute__((ext_vector_type(4))) uint u32x4;
typedef __attribute__((ext_vector_type(8))) __bf16 bf16x8;

#define MFMA16(a,b,c) __builtin_amdgcn_mfma_f32_16x16x32_bf16(a,b,c,0,0,0)

__device__ __forceinline__ ushort f2bf(float f){
  uint u = __float_as_uint(f);
  u += 0x7fffu + ((u>>16)&1u);
  return (ushort)(u>>16);
}
__device__ __forceinline__ float bf2f(ushort s){ return __uint_as_float(((uint)s)<<16); }
__device__ __forceinline__ uint packbf2(float a, float b){ return (uint)f2bf(a) | ((uint)f2bf(b)<<16); }

// ---------------- tiled weight transpose, z-batched over all 5 weights ----------------
// W[K][N] fp32 -> WT[N][K] bf16. 64x64 tile; bf16 in 4B LDS slots, stride 65 words.
struct WtArgs { const float* W[5]; ushort* T[5]; int K[5]; int N[5]; };

__global__ __launch_bounds__(256) void wt_kernel(WtArgs args){
  __shared__ uint tile[64*65];
  const int z = blockIdx.z;
  const float* __restrict__ W = args.W[z];
  ushort* __restrict__ WT = args.T[z];
  const int K = args.K[z], N = args.N[z];
  const int k0 = blockIdx.y<<6, n0 = blockIdx.x<<6;
  if (n0 >= N || k0 >= K) return;      // block-uniform: Wx (N=128) uses 2 of 8 x-blocks
  const int tid = threadIdx.x;
  {
    const int row = tid>>4, c4 = (tid&15)<<2;
    #pragma unroll
    for (int i=0;i<4;++i){
      int r = row + (i<<4);
      float4 v = *reinterpret_cast<const float4*>(W + (size_t)(k0+r)*N + n0 + c4);
      tile[r*65 + c4    ] = f2bf(v.x);
      tile[r*65 + c4 + 1] = f2bf(v.y);
      tile[r*65 + c4 + 2] = f2bf(v.z);
      tile[r*65 + c4 + 3] = f2bf(v.w);
    }
  }
  __syncthreads();
  {
    const int n = tid>>3, k8 = (tid&7)<<3;
    #pragma unroll
    for (int j=0;j<2;++j){
      int nn = n + (j<<5);
      ushort t0=(ushort)tile[(k8+0)*65+nn], t1=(ushort)tile[(k8+1)*65+nn];
      ushort t2=(ushort)tile[(k8+2)*65+nn], t3=(ushort)tile[(k8+3)*65+nn];
      ushort t4=(ushort)tile[(k8+4)*65+nn], t5=(ushort)tile[(k8+5)*65+nn];
      ushort t6=(ushort)tile[(k8+6)*65+nn], t7=(ushort)tile[(k8+7)*65+nn];
      uint4 pk = make_uint4((uint)t0|((uint)t1<<16), (uint)t2|((uint)t3<<16),
                            (uint)t4|((uint)t5<<16), (uint)t6|((uint)t7<<16));
      *reinterpret_cast<uint4*>(WT + (size_t)(n0+nn)*K + k0 + k8) = pk;
    }
  }
}

// ---------------- bf16 MFMA GEMM body: C = A[M,K] * Bt[N,K]^T + bias ----------------
// Register double-buffer: next K-tile's global loads issue under current tile's MFMAs.
template<bool A_F32, bool OUT_F32>
__device__ __forceinline__ void gemm_body(ushort* As, ushort* Bs,
    const void* __restrict__ Av, const ushort* __restrict__ Bt,
    const float* __restrict__ bias, void* __restrict__ Cv, int M, int N, int K){
  const int tid = threadIdx.x;
  const int m0 = blockIdx.y<<6, n0 = blockIdx.x<<6;
  const int wave = tid>>6, lane = tid&63;
  const int wr = wave&1, wc = wave>>1;
  const int fl = lane&15, quad = lane>>4;
  f32x4 acc[2][2] = {};
  const int srow = tid>>2, sk = (tid&3)<<3;
  float4 va0, va1; uint4 ua; uint4 ub;
  // prologue: first K-tile into registers
  if (A_F32){
    const float4* pa = reinterpret_cast<const float4*>((const float*)Av + (size_t)(m0+srow)*K + sk);
    va0 = pa[0]; va1 = pa[1];
  } else {
    ua = *reinterpret_cast<const uint4*>((const ushort*)Av + (size_t)(m0+srow)*K + sk);
  }
  ub = *reinterpret_cast<const uint4*>(Bt + (size_t)(n0+srow)*K + sk);
  for (int k0 = 0; k0 < K; k0 += 32){
    if (A_F32){
      *reinterpret_cast<uint4*>(&As[srow*48 + sk]) = make_uint4(
          packbf2(va0.x,va0.y), packbf2(va0.z,va0.w),
          packbf2(va1.x,va1.y), packbf2(va1.z,va1.w));
    } else {
      *reinterpret_cast<uint4*>(&As[srow*48 + sk]) = ua;
    }
    *reinterpret_cast<uint4*>(&Bs[srow*48 + sk]) = ub;
    __syncthreads();
    const int kn = k0 + 32;
    if (kn < K){                       // issue next tile's loads; latency hides under MFMA
      if (A_F32){
        const float4* pa = reinterpret_cast<const float4*>((const float*)Av + (size_t)(m0+srow)*K + kn + sk);
        va0 = pa[0]; va1 = pa[1];
      } else {
        ua = *reinterpret_cast<const uint4*>((const ushort*)Av + (size_t)(m0+srow)*K + kn + sk);
      }
      ub = *reinterpret_cast<const uint4*>(Bt + (size_t)(n0+srow)*K + kn + sk);
    }
    bf16x8 a0 = *reinterpret_cast<const bf16x8*>(&As[(32*wr      + fl)*48 + quad*8]);
    bf16x8 a1 = *reinterpret_cast<const bf16x8*>(&As[(32*wr + 16 + fl)*48 + quad*8]);
    bf16x8 b0 = *reinterpret_cast<const bf16x8*>(&Bs[(32*wc      + fl)*48 + quad*8]);
    bf16x8 b1 = *reinterpret_cast<const bf16x8*>(&Bs[(32*wc + 16 + fl)*48 + quad*8]);
    acc[0][0] = MFMA16(a0,b0,acc[0][0]);
    acc[0][1] = MFMA16(a0,b1,acc[0][1]);
    acc[1][0] = MFMA16(a1,b0,acc[1][0]);
    acc[1][1] = MFMA16(a1,b1,acc[1][1]);
    __syncthreads();
  }
  #pragma unroll
  for (int t=0;t<2;++t)
  #pragma unroll
  for (int u=0;u<2;++u){
    #pragma unroll
    for (int r=0;r<4;++r){
      int row = m0 + 32*wr + 16*t + quad*4 + r;
      int col = n0 + 32*wc + 16*u + fl;
      float vv = acc[t][u][r] + bias[col];
      if (OUT_F32) ((float*)Cv)[(size_t)row*N + col] = vv;
      else         ((ushort*)Cv)[(size_t)row*N + col] = f2bf(vv);
    }
  }
}

template<bool A_F32, bool OUT_F32>
__global__ __launch_bounds__(256) void gemm_bt(const void* __restrict__ Av,
    const ushort* __restrict__ Bt, const float* __restrict__ bias,
    void* __restrict__ Cv, int M, int N, int K){
  __shared__ ushort As[64*48];
  __shared__ ushort Bs[64*48];
  gemm_body<A_F32,OUT_F32>(As, Bs, Av, Bt, bias, Cv, M, N, K);
}

// q/k/v projections in one launch (z selects the triple)
__global__ __launch_bounds__(256) void gemm3_kernel(
    const float* A0, const float* A1, const float* A2,
    const ushort* T0, const ushort* T1, const ushort* T2,
    const float* b0, const float* b1, const float* b2,
    ushort* C0, ushort* C1, ushort* C2, int M, int N, int K){
  __shared__ ushort As[64*48];
  __shared__ ushort Bs[64*48];
  const int z = blockIdx.z;
  const float* A = z==0 ? A0 : (z==1 ? A1 : A2);
  const ushort* Bt = z==0 ? T0 : (z==1 ? T1 : T2);
  const float* bi = z==0 ? b0 : (z==1 ? b1 : b2);
  ushort* C = z==0 ? C0 : (z==1 ? C1 : C2);
  gemm_body<true,false>(As, Bs, A, Bt, bi, C, M, N, K);
}

// ---------------- vp [B*S, 512] bf16 -> vT [(b*8+h)*64 + d][1024 k] bf16 ----------------
__global__ __launch_bounds__(256) void vtrans(const ushort* __restrict__ vp,
    ushort* __restrict__ vT){
  __shared__ ushort tile[64*72];
  const int bh = blockIdx.y;            // b*8 + h
  const int b = bh>>3, h = bh&7;
  const int k0 = blockIdx.x<<6;
  const int tid = threadIdx.x;
  #pragma unroll
  for (int i=0;i<2;++i){
    int c = tid + (i<<8);
    int row = c>>3, ch = (c&7)<<3;
    uint4 v = *reinterpret_cast<const uint4*>(
        vp + ((size_t)(b*1024 + k0 + row)<<9) + (h<<6) + ch);
    *reinterpret_cast<uint4*>(&tile[row*72 + ch]) = v;
  }
  __syncthreads();
  #pragma unroll
  for (int i=0;i<2;++i){
    int c = tid + (i<<8);
    int d = c>>3, sc = (c&7)<<3;
    ushort t0 = tile[(sc+0)*72 + d], t1 = tile[(sc+1)*72 + d];
    ushort t2 = tile[(sc+2)*72 + d], t3 = tile[(sc+3)*72 + d];
    ushort t4 = tile[(sc+4)*72 + d], t5 = tile[(sc+5)*72 + d];
    ushort t6 = tile[(sc+6)*72 + d], t7 = tile[(sc+7)*72 + d];
    uint4 pk = make_uint4((uint)t0|((uint)t1<<16), (uint)t2|((uint)t3<<16),
                          (uint)t4|((uint)t5<<16), (uint)t6|((uint)t7<<16));
    *reinterpret_cast<uint4*>(vT + (((size_t)bh<<6) + d)*1024 + k0 + sc) = pk;
  }
}

// ---------------- xl[b,h,q,k] = bf16( 0.5 * sum_f xdiff[b,q,k,f]*xh[b,q,h,f] ) ----------------
// xdiff rows staged in registers (64 VGPRs), h-outer loop -> 4x fewer LDS broadcast reads.
__global__ __launch_bounds__(256) void xl_kernel(const float* __restrict__ xdiff,
    const ushort* __restrict__ xb, ushort* __restrict__ xl){
  const int bq = blockIdx.x;            // b*1024 + q
  const int b = bq>>10, q = bq&1023;
  __shared__ float sx[8][16];
  const int tid = threadIdx.x;
  if (tid < 128) sx[tid>>4][tid&15] = bf2f(xb[(size_t)bq*128 + tid]);
  __syncthreads();
  const float* xd = xdiff + (size_t)bq*16384;
  f32x4 v[4][4];
  #pragma unroll
  for (int i=0;i<4;++i){
    int k = tid + (i<<8);
    const f32x4* p = reinterpret_cast<const f32x4*>(xd + (size_t)k*16);
    #pragma unroll
    for (int j=0;j<4;++j) v[i][j] = __builtin_nontemporal_load(p + j);
  }
  #pragma unroll
  for (int h=0; h<8; ++h){
    const float4* s = reinterpret_cast<const float4*>(&sx[h][0]);
    float4 s0=s[0], s1=s[1], s2=s[2], s3=s[3];
    #pragma unroll
    for (int i=0;i<4;++i){
      int k = tid + (i<<8);
      float a = v[i][0].x*s0.x + v[i][0].y*s0.y + v[i][0].z*s0.z + v[i][0].w*s0.w
              + v[i][1].x*s1.x + v[i][1].y*s1.y + v[i][1].z*s1.z + v[i][1].w*s1.w
              + v[i][2].x*s2.x + v[i][2].y*s2.y + v[i][2].z*s2.z + v[i][2].w*s2.w
              + v[i][3].x*s3.x + v[i][3].y*s3.y + v[i][3].z*s3.z + v[i][3].w*s3.w;
      xl[(((size_t)((b<<3)+h)<<10) + q)*1024 + k] = f2bf(0.5f*a);
    }
  }
}

// ---------------- fused attention: logits -> softmax -> attn out + PV ----------------
// 512 threads = 8 waves. Softmax is register-resident: biased logits / exp values stay
// bf16-packed in rg[8] (32 VGPRs); LDS is touched once by QK-write, once by softmax read,
// once by normalized write, once by PV read (was 8 sweeps).
__global__ __launch_bounds__(512,4) void attn_kernel(const ushort* __restrict__ qp,
    const ushort* __restrict__ kp, const ushort* __restrict__ vT,
    const ushort* __restrict__ xl, float* __restrict__ attn, ushort* __restrict__ outc){
  __shared__ ushort s_p[32*1024];       // 64 KB
  const int qt = blockIdx.x, h = blockIdx.y, b = blockIdx.z;
  const int q0 = qt<<5;
  const int tid = threadIdx.x, lane = tid&63, wave = tid>>6;
  const int wr = wave&1, wc = wave>>1;  // wc in 0..3
  const int fl = lane&15, quad = lane>>4;
  const size_t bS = (size_t)b<<10;
  const int bh = (b<<3) + h;

  // Q fragments (A-operand: m = lane&15, k = quad*8+j)
  bf16x8 aq[2];
  #pragma unroll
  for (int s=0;s<2;++s)
    aq[s] = *reinterpret_cast<const bf16x8*>(
        qp + ((bS + q0 + (wr<<4) + fl)<<9) + (h<<6) + (s<<5) + (quad<<3));

  // ---- QK^T: 16 key-tiles of 64; unroll 4 for memory-level parallelism ----
  #pragma unroll 4
  for (int kt=0; kt<16; ++kt){
    f32x4 acc = {};
    #pragma unroll
    for (int s=0;s<2;++s){
      bf16x8 bfr = *reinterpret_cast<const bf16x8*>(
          kp + ((bS + (kt<<6) + (wc<<4) + fl)<<9) + (h<<6) + (s<<5) + (quad<<3));
      acc = MFMA16(aq[s], bfr, acc);
    }
    #pragma unroll
    for (int r=0;r<4;++r){
      int row = (wr<<4) + (quad<<2) + r;
      int col = (kt<<6) + (wc<<4) + fl;
      int chunk = (col>>3) ^ ((row>>1)&7);
      s_p[(row<<10) + (chunk<<3) + (col&7)] = f2bf(acc[r]*0.125f);
    }
  }
  __syncthreads();

  // ---- softmax: 16 threads per row; data lives in rg[8] between passes ----
  const int r = tid>>4, seg = tid&15, swz = (r>>1)&7;
  const ushort* xrow = xl + (((size_t)bh<<10) + q0 + r)*1024;
  float* arow = attn + (((size_t)bh<<10) + q0 + r)*1024;
  uint4 rg[8];
  float mx = -3.0e38f;
  #pragma unroll
  for (int cc=0; cc<8; ++cc){          // pass 1: logits + xl bias, track max (LDS read only)
    int chunk = (cc<<4) + seg;
    uint4 lv = *reinterpret_cast<uint4*>(&s_p[(r<<10) + ((chunk^swz)<<3)]);
    u32x4 xv = __builtin_nontemporal_load(
        reinterpret_cast<const u32x4*>(xrow + (chunk<<3)));
    float f0 = bf2f(lv.x&0xffff)+bf2f(xv.x&0xffff), f1 = bf2f(lv.x>>16)+bf2f(xv.x>>16);
    float f2 = bf2f(lv.y&0xffff)+bf2f(xv.y&0xffff), f3 = bf2f(lv.y>>16)+bf2f(xv.y>>16);
    float f4 = bf2f(lv.z&0xffff)+bf2f(xv.z&0xffff), f5 = bf2f(lv.z>>16)+bf2f(xv.z>>16);
    float f6 = bf2f(lv.w&0xffff)+bf2f(xv.w&0xffff), f7 = bf2f(lv.w>>16)+bf2f(xv.w>>16);
    mx = fmaxf(mx, fmaxf(fmaxf(fmaxf(f0,f1),fmaxf(f2,f3)), fmaxf(fmaxf(f4,f5),fmaxf(f6,f7))));
    rg[cc] = make_uint4(packbf2(f0,f1), packbf2(f2,f3), packbf2(f4,f5), packbf2(f6,f7));
  }
  #pragma unroll
  for (int d=1; d<16; d<<=1) mx = fmaxf(mx, __shfl_xor(mx, d));
  float sum = 0.f;
  #pragma unroll
  for (int cc=0; cc<8; ++cc){          // pass 2: exp in registers, bf16-round, sum
    uint4 lv = rg[cc];
    ushort u0 = f2bf(__expf(bf2f(lv.x&0xffff)-mx)), u1 = f2bf(__expf(bf2f(lv.x>>16)-mx));
    ushort u2 = f2bf(__expf(bf2f(lv.y&0xffff)-mx)), u3 = f2bf(__expf(bf2f(lv.y>>16)-mx));
    ushort u4 = f2bf(__expf(bf2f(lv.z&0xffff)-mx)), u5 = f2bf(__expf(bf2f(lv.z>>16)-mx));
    ushort u6 = f2bf(__expf(bf2f(lv.w&0xffff)-mx)), u7 = f2bf(__expf(bf2f(lv.w>>16)-mx));
    sum += bf2f(u0)+bf2f(u1)+bf2f(u2)+bf2f(u3)+bf2f(u4)+bf2f(u5)+bf2f(u6)+bf2f(u7);
    rg[cc] = make_uint4((uint)u0|((uint)u1<<16), (uint)u2|((uint)u3<<16),
                        (uint)u4|((uint)u5<<16), (uint)u6|((uint)u7<<16));
  }
  #pragma unroll
  for (int d=1; d<16; d<<=1) sum += __shfl_xor(sum, d);
  float inv = 1.f/sum;
  #pragma unroll
  for (int cc=0; cc<8; ++cc){          // pass 3: normalize; nt-store fp32 attn; bf16 -> LDS
    int chunk = (cc<<4) + seg;
    uint4 lv = rg[cc];
    float o0 = bf2f(lv.x&0xffff)*inv, o1 = bf2f(lv.x>>16)*inv;
    float o2 = bf2f(lv.y&0xffff)*inv, o3 = bf2f(lv.y>>16)*inv;
    float o4 = bf2f(lv.z&0xffff)*inv, o5 = bf2f(lv.z>>16)*inv;
    float o6 = bf2f(lv.w&0xffff)*inv, o7 = bf2f(lv.w>>16)*inv;
    __builtin_nontemporal_store(f32x4{o0,o1,o2,o3},
        reinterpret_cast<f32x4*>(arow + (chunk<<3)));
    __builtin_nontemporal_store(f32x4{o4,o5,o6,o7},
        reinterpret_cast<f32x4*>(arow + (chunk<<3) + 4));
    *reinterpret_cast<uint4*>(&s_p[(r<<10) + ((chunk^swz)<<3)]) =
        make_uint4(packbf2(o0,o1), packbf2(o2,o3), packbf2(o4,o5), packbf2(o6,o7));
  }
  __syncthreads();

  // ---- PV: out[32 q][64 d]; each wave computes 16q x 16d ----
  f32x4 o = {};
  const int ar = (wr<<4) + fl;
  const int aswz = (ar>>1)&7;
  #pragma unroll 2
  for (int kt=0; kt<16; ++kt){
    #pragma unroll
    for (int s=0;s<2;++s){
      int chunk = (kt<<3) + (s<<2) + quad;
      bf16x8 af = *reinterpret_cast<const bf16x8*>(&s_p[(ar<<10) + ((chunk^aswz)<<3)]);
      bf16x8 bfr = *reinterpret_cast<const bf16x8*>(
          vT + (((size_t)bh<<6) + (wc<<4) + fl)*1024 + (kt<<6) + (s<<5) + (quad<<3));
      o = MFMA16(af, bfr, o);
    }
  }
  #pragma unroll
  for (int r4=0;r4<4;++r4){
    int row = (wr<<4) + (quad<<2) + r4;
    int col = (wc<<4) + fl;
    outc[((bS + q0 + row)<<9) + (h<<6) + col] = f2bf(o[r4]);
  }
}

extern "C" void kernel_launch(void* const* d_in, const int* in_sizes, int n_in,
                              void* d_out, int out_size, void* d_ws, size_t ws_size,
                              hipStream_t stream){
  (void)in_sizes; (void)n_in; (void)out_size; (void)ws_size;
  const float* q  = (const float*)d_in[0];
  const float* k  = (const float*)d_in[1];
  const float* v  = (const float*)d_in[2];
  const float* xd = (const float*)d_in[3];
  const float* Wq = (const float*)d_in[4];  const float* bq = (const float*)d_in[5];
  const float* Wk = (const float*)d_in[6];  const float* bk = (const float*)d_in[7];
  const float* Wv = (const float*)d_in[8];  const float* bv = (const float*)d_in[9];
  const float* Wx = (const float*)d_in[10]; const float* bx = (const float*)d_in[11];
  const float* Wo = (const float*)d_in[12]; const float* bo = (const float*)d_in[13];
  char* ws = (char*)d_ws;
  const size_t MB = 1u<<20;
  ushort* qp  = (ushort*)(ws);                 // [4096][512] bf16  (4 MB)
  ushort* kp  = (ushort*)(ws + 4*MB);
  ushort* vp  = (ushort*)(ws + 8*MB);
  ushort* vT  = (ushort*)(ws + 12*MB);         // [32*64][1024] bf16
  ushort* xb  = (ushort*)(ws + 16*MB);         // [4096][128] bf16  (1 MB)
  ushort* xl  = (ushort*)(ws + 17*MB);         // [4,8,1024,1024] bf16 (64 MB)
  ushort* oc  = (ushort*)(ws + 81*MB);         // [4096][512] bf16
  ushort* WqT = (ushort*)(ws + 85*MB);
  ushort* WkT = (ushort*)(ws + 85*MB + 1*524288);
  ushort* WvT = (ushort*)(ws + 85*MB + 2*524288);
  ushort* WoT = (ushort*)(ws + 85*MB + 3*524288);
  ushort* WxT = (ushort*)(ws + 85*MB + 4*524288);
  float* out0 = (float*)d_out;                 // [4,1024,512] fp32
  float* attn = (float*)d_out + 2097152;       // [4,8,1024,1024] fp32

  WtArgs wa;
  wa.W[0]=Wq; wa.W[1]=Wk; wa.W[2]=Wv; wa.W[3]=Wo; wa.W[4]=Wx;
  wa.T[0]=WqT; wa.T[1]=WkT; wa.T[2]=WvT; wa.T[3]=WoT; wa.T[4]=WxT;
  wa.K[0]=512; wa.K[1]=512; wa.K[2]=512; wa.K[3]=512; wa.K[4]=512;
  wa.N[0]=512; wa.N[1]=512; wa.N[2]=512; wa.N[3]=512; wa.N[4]=128;
  wt_kernel<<<dim3(8,8,5), 256, 0, stream>>>(wa);

  gemm3_kernel<<<dim3(8,64,3), 256, 0, stream>>>(q, k, v, WqT, WkT, WvT,
                                                 bq, bk, bv, qp, kp, vp, 4096, 512, 512);
  gemm_bt<false,false><<<dim3(2,64), 256, 0, stream>>>(qp, WxT, bx, xb, 4096, 128, 512);

  vtrans<<<dim3(16,32), 256, 0, stream>>>(vp, vT);
  xl_kernel<<<4096, 256, 0, stream>>>(xd, xb, xl);
  attn_kernel<<<dim3(32,8,4), 512, 0, stream>>>(qp, kp, vT, xl, attn, oc);
  gemm_bt<false,true><<<dim3(8,64), 256, 0, stream>>>(oc, WoT, bo, out0, 4096, 512, 512);
}